// Round 1
// baseline (1136.265 us; speedup 1.0000x reference)
//
#include <hip/hip_runtime.h>

#define NF 128
#define EPS 1e-5f

// ---------------- small utility kernels ----------------

__global__ void k_fill(float* p, float v, int n) {
    int i = blockIdx.x * 256 + threadIdx.x;
    if (i < n) p[i] = v;
}

__global__ void k_deg(const int* __restrict__ ei, float* deg, int E) {
    int e = blockIdx.x * 256 + threadIdx.x;
    if (e < E) atomicAdd(&deg[ei[e]], 1.0f);  // src occurrences
}

__global__ void k_rsqrt(float* p, int n) {
    int i = blockIdx.x * 256 + threadIdx.x;
    if (i < n) p[i] = rsqrtf(p[i]);  // deg >= 1 always (self-loop)
}

__global__ void k_count(const int* __restrict__ ei, int* cnt, int E) {
    int e = blockIdx.x * 256 + threadIdx.x;
    if (e < E) atomicAdd(&cnt[ei[E + e]], 1);  // dst histogram
}

// single-block inclusive scan -> rowptr[0..n], cursor copy
__global__ void scan_csr(const int* __restrict__ cnt, int* __restrict__ rowptr,
                         int* __restrict__ cursor, int n) {
    __shared__ int lds[1024];
    int tid = threadIdx.x;
    int carry = 0;
    if (tid == 0) { rowptr[0] = 0; cursor[0] = 0; }
    for (int base = 0; base < n; base += 1024) {
        int i = base + tid;
        int v = (i < n) ? cnt[i] : 0;
        lds[tid] = v;
        __syncthreads();
        for (int off = 1; off < 1024; off <<= 1) {
            int t = (tid >= off) ? lds[tid - off] : 0;
            __syncthreads();
            lds[tid] += t;
            __syncthreads();
        }
        int incl = lds[tid];
        int total = lds[1023];
        if (i < n) { rowptr[i + 1] = carry + incl; cursor[i + 1] = carry + incl; }
        carry += total;
        __syncthreads();
    }
}

__global__ void k_fill_csr(const int* __restrict__ ei, const float* __restrict__ dinv,
                           int* cursor, int* __restrict__ colx, float* __restrict__ wtx,
                           int E) {
    int e = blockIdx.x * 256 + threadIdx.x;
    if (e < E) {
        int s = ei[e], d = ei[E + e];
        int pos = atomicAdd(&cursor[d], 1);
        colx[pos] = s;
        wtx[pos] = dinv[s] * dinv[d];
    }
}

// ---------------- batch norm ----------------

// column sums / sumsq of h[n][128] into stats[0..127]=sum, [128..255]=sumsq
__global__ void bn_stats(const float* __restrict__ h, float* __restrict__ stats, int n) {
    int j = threadIdx.x & 127;
    int half = threadIdx.x >> 7;  // 0/1
    float s = 0.f, q = 0.f;
    for (int r = blockIdx.x * 2 + half; r < n; r += gridDim.x * 2) {
        float v = h[r * NF + j];
        s += v;
        q += v * v;
    }
    __shared__ float ls[256], lq[256];
    ls[threadIdx.x] = s; lq[threadIdx.x] = q;
    __syncthreads();
    if (threadIdx.x < 128) {
        atomicAdd(&stats[j], ls[threadIdx.x] + ls[threadIdx.x + 128]);
        atomicAdd(&stats[NF + j], lq[threadIdx.x] + lq[threadIdx.x + 128]);
    }
}

// ac[0..127] = a = g*rstd ; ac[128..255] = c = b - mean*a
__global__ void bn_finalize(const float* __restrict__ stats, const float* __restrict__ g,
                            const float* __restrict__ b, float* __restrict__ ac,
                            float inv_n) {
    int j = threadIdx.x;  // 128 threads
    float mean = stats[j] * inv_n;
    float var = stats[NF + j] * inv_n - mean * mean;
    float rstd = rsqrtf(var + EPS);
    float a = g[j] * rstd;
    ac[j] = a;
    ac[NF + j] = b[j] - mean * a;
}

// ---------------- GEMM: out = opt_relu( (h*a + c) @ W + opt_bias ) ----------------
// h [nrows][128], W [128][128]. Tile: 64 rows x 128 cols, 256 threads, 4x8 per thread.

__launch_bounds__(256)
__global__ void gemm_bn(const float* __restrict__ Hh, const float* __restrict__ W,
                        const float* __restrict__ ac, const float* __restrict__ bias,
                        float* __restrict__ out, int nrows, int relu) {
    __shared__ float hs[64][133];  // pad 133: a-reads land 2-way max (free)
    const int tid = threadIdx.x;
    const int tx = tid & 15;   // 16 col groups
    const int ty = tid >> 4;   // 16 row groups
    const int rb = blockIdx.x * 64;

    // stage h tile with BN applied (coalesced along k)
#pragma unroll 8
    for (int p = 0; p < 32; ++p) {
        int idx = p * 256 + tid;
        int r = idx >> 7, k = idx & 127;
        int gr = rb + r;
        float v = (gr < nrows) ? Hh[(size_t)gr * NF + k] : 0.f;
        hs[r][k] = fmaf(v, ac[k], ac[NF + k]);
    }
    __syncthreads();

    float acc[4][8];
#pragma unroll
    for (int i = 0; i < 4; ++i)
#pragma unroll
        for (int j = 0; j < 8; ++j) acc[i][j] = 0.f;

    const int c0 = tx * 4, c1 = 64 + tx * 4;
#pragma unroll 4
    for (int k = 0; k < 128; ++k) {
        const float4 b0 = *(const float4*)&W[k * NF + c0];
        const float4 b1 = *(const float4*)&W[k * NF + c1];
#pragma unroll
        for (int i = 0; i < 4; ++i) {
            float a = hs[ty * 4 + i][k];
            acc[i][0] = fmaf(a, b0.x, acc[i][0]);
            acc[i][1] = fmaf(a, b0.y, acc[i][1]);
            acc[i][2] = fmaf(a, b0.z, acc[i][2]);
            acc[i][3] = fmaf(a, b0.w, acc[i][3]);
            acc[i][4] = fmaf(a, b1.x, acc[i][4]);
            acc[i][5] = fmaf(a, b1.y, acc[i][5]);
            acc[i][6] = fmaf(a, b1.z, acc[i][6]);
            acc[i][7] = fmaf(a, b1.w, acc[i][7]);
        }
    }

#pragma unroll
    for (int i = 0; i < 4; ++i) {
        int gr = rb + ty * 4 + i;
        if (gr < nrows) {
            float o[8];
#pragma unroll
            for (int j = 0; j < 8; ++j) {
                int c = (j < 4) ? (c0 + j) : (c1 + j - 4);
                float v = acc[i][j] + (bias ? bias[c] : 0.f);
                o[j] = relu ? fmaxf(v, 0.f) : v;
            }
            *(float4*)&out[(size_t)gr * NF + c0] = make_float4(o[0], o[1], o[2], o[3]);
            *(float4*)&out[(size_t)gr * NF + c1] = make_float4(o[4], o[5], o[6], o[7]);
        }
    }
}

// ---------------- GCN aggregation (CSR gather) ----------------
// out[i] = relu( xw[i]*dinv[i]^2 + sum_e xw[col[e]]*wt[e] + bias )

__launch_bounds__(256)
__global__ void k_aggregate(const float* __restrict__ xw, const int* __restrict__ rowptr,
                            const int* __restrict__ colx, const float* __restrict__ wtx,
                            const float* __restrict__ dinv, const float* __restrict__ bias,
                            float* __restrict__ out, int n) {
    int node = blockIdx.x * 2 + (threadIdx.x >> 7);
    int j = threadIdx.x & 127;
    if (node >= n) return;
    float di = dinv[node];
    float acc = xw[(size_t)node * NF + j] * (di * di);  // self loop
    int e0 = rowptr[node], e1 = rowptr[node + 1];
    for (int e = e0; e < e1; ++e) {
        int s = colx[e];
        float w = wtx[e];
        acc = fmaf(xw[(size_t)s * NF + j], w, acc);
    }
    out[(size_t)node * NF + j] = fmaxf(acc + bias[j], 0.f);
}

// ---------------- pooling ----------------

__global__ void k_pool(const float* __restrict__ h, const int* __restrict__ batch,
                       float* __restrict__ pooled, int n) {
    int idx = blockIdx.x * 256 + threadIdx.x;
    if (idx < n * NF) {
        int r = idx >> 7, j = idx & 127;
        atomicAdd(&pooled[batch[r] * NF + j], h[idx]);
    }
}

// ---------------- classifier + log_softmax ----------------

__global__ void k_cls(const float* __restrict__ h, const float* __restrict__ ac,
                      const float* __restrict__ Wc, const float* __restrict__ bc,
                      float* __restrict__ out, int C_) {
    __shared__ float hr[128];
    __shared__ float lg[16];
    __shared__ float lse_s;
    int r = blockIdx.x, t = threadIdx.x;  // 64 threads
    hr[t]      = fmaf(h[r * NF + t],      ac[t],      ac[NF + t]);
    hr[t + 64] = fmaf(h[r * NF + 64 + t], ac[64 + t], ac[NF + 64 + t]);
    __syncthreads();
    if (t < C_) {
        float s = bc[t];
        for (int k = 0; k < 128; ++k) s = fmaf(hr[k], Wc[k * C_ + t], s);
        lg[t] = s;
    }
    __syncthreads();
    if (t == 0) {
        float m = -1e30f;
        for (int c = 0; c < C_; ++c) m = fmaxf(m, lg[c]);
        float se = 0.f;
        for (int c = 0; c < C_; ++c) se += expf(lg[c] - m);
        lse_s = m + logf(se);
    }
    __syncthreads();
    if (t < C_) out[r * C_ + t] = lg[t] - lse_s;
}

// ---------------- launch ----------------

extern "C" void kernel_launch(void* const* d_in, const int* in_sizes, int n_in,
                              void* d_out, int out_size, void* d_ws, size_t ws_size,
                              hipStream_t stream) {
    const float* x          = (const float*)d_in[0];
    const int*   ei         = (const int*)d_in[1];
    const int*   batch      = (const int*)d_in[2];
    const float* bn_feat_g  = (const float*)d_in[3];
    const float* bn_feat_b  = (const float*)d_in[4];
    const float* W_feat     = (const float*)d_in[5];
    const float* bns_conv_g = (const float*)d_in[6];
    const float* bns_conv_b = (const float*)d_in[7];
    const float* W_conv     = (const float*)d_in[8];
    const float* b_conv     = (const float*)d_in[9];
    const float* bn_fc_g    = (const float*)d_in[10];
    const float* bn_fc_b    = (const float*)d_in[11];
    const float* W_lin      = (const float*)d_in[12];
    const float* b_lin      = (const float*)d_in[13];
    const float* bn_hid_g   = (const float*)d_in[14];
    const float* bn_hid_b   = (const float*)d_in[15];
    const float* W_cls      = (const float*)d_in[16];
    const float* b_cls      = (const float*)d_in[17];
    float* outp = (float*)d_out;

    const int N_ = in_sizes[2];
    const int E_ = in_sizes[1] / 2;
    const int C_ = 10;
    const int G_ = out_size / C_;

    // workspace layout
    char* wsp = (char*)d_ws;
    auto alloc = [&](size_t bytes) {
        void* p = (void*)wsp;
        wsp += (bytes + 255) & ~(size_t)255;
        return p;
    };
    float* A      = (float*)alloc((size_t)N_ * NF * 4);
    float* B      = (float*)alloc((size_t)N_ * NF * 4);
    float* dinv   = (float*)alloc((size_t)N_ * 4);
    int*   cnt    = (int*)alloc((size_t)N_ * 4);
    int*   rowptr = (int*)alloc((size_t)(N_ + 1) * 4);
    int*   cursor = (int*)alloc((size_t)(N_ + 1) * 4);
    int*   colx   = (int*)alloc((size_t)E_ * 4);
    float* wtx    = (float*)alloc((size_t)E_ * 4);
    float* stats  = (float*)alloc(256 * 4);
    float* ac     = (float*)alloc(256 * 4);
    float* pooled = (float*)alloc((size_t)G_ * NF * 4);
    float* y2     = (float*)alloc((size_t)G_ * NF * 4);

    int nb_n = (N_ + 255) / 256;
    int nb_e = (E_ + 255) / 256;

    // graph prep: degrees (src + self-loop), dinv, dst-CSR
    k_fill<<<nb_n, 256, 0, stream>>>(dinv, 1.0f, N_);
    k_deg<<<nb_e, 256, 0, stream>>>(ei, dinv, E_);
    k_rsqrt<<<nb_n, 256, 0, stream>>>(dinv, N_);
    hipMemsetAsync(cnt, 0, (size_t)N_ * 4, stream);
    k_count<<<nb_e, 256, 0, stream>>>(ei, cnt, E_);
    scan_csr<<<1, 1024, 0, stream>>>(cnt, rowptr, cursor, N_);
    k_fill_csr<<<nb_e, 256, 0, stream>>>(ei, dinv, cursor, colx, wtx, E_);

    // feat: h = relu( bn(x) @ W_feat )
    hipMemsetAsync(stats, 0, 256 * 4, stream);
    bn_stats<<<512, 256, 0, stream>>>(x, stats, N_);
    bn_finalize<<<1, 128, 0, stream>>>(stats, bn_feat_g, bn_feat_b, ac, 1.0f / N_);
    gemm_bn<<<(N_ + 63) / 64, 256, 0, stream>>>(x, W_feat, ac, nullptr, A, N_, 1);

    // conv layers
    for (int l = 0; l < 3; ++l) {
        hipMemsetAsync(stats, 0, 256 * 4, stream);
        bn_stats<<<512, 256, 0, stream>>>(A, stats, N_);
        bn_finalize<<<1, 128, 0, stream>>>(stats, bns_conv_g + l * NF, bns_conv_b + l * NF,
                                           ac, 1.0f / N_);
        gemm_bn<<<(N_ + 63) / 64, 256, 0, stream>>>(A, W_conv + (size_t)l * NF * NF, ac,
                                                    nullptr, B, N_, 0);
        k_aggregate<<<(N_ + 1) / 2, 256, 0, stream>>>(B, rowptr, colx, wtx, dinv,
                                                      b_conv + l * NF, A, N_);
    }

    // pool
    hipMemsetAsync(pooled, 0, (size_t)G_ * NF * 4, stream);
    k_pool<<<((N_ * NF) + 255) / 256, 256, 0, stream>>>(A, batch, pooled, N_);

    // fc: y2 = relu( bn(pooled) @ W_lin + b_lin )
    hipMemsetAsync(stats, 0, 256 * 4, stream);
    bn_stats<<<512, 256, 0, stream>>>(pooled, stats, G_);
    bn_finalize<<<1, 128, 0, stream>>>(stats, bn_fc_g, bn_fc_b, ac, 1.0f / G_);
    gemm_bn<<<(G_ + 63) / 64, 256, 0, stream>>>(pooled, W_lin, ac, b_lin, y2, G_, 1);

    // classifier: out = log_softmax( bn(y2) @ W_cls + b_cls )
    hipMemsetAsync(stats, 0, 256 * 4, stream);
    bn_stats<<<512, 256, 0, stream>>>(y2, stats, G_);
    bn_finalize<<<1, 128, 0, stream>>>(stats, bn_hid_g, bn_hid_b, ac, 1.0f / G_);
    k_cls<<<G_, 64, 0, stream>>>(y2, ac, W_cls, b_cls, outp, C_);
}

// Round 2
// 896.478 us; speedup vs baseline: 1.2675x; 1.2675x over previous
//
#include <hip/hip_runtime.h>

#define NF 128
#define EPS 1e-5f

// ---------------- small utility kernels ----------------

__global__ void k_fill(float* p, float v, int n) {
    int i = blockIdx.x * 256 + threadIdx.x;
    if (i < n) p[i] = v;
}

__global__ void k_deg(const int* __restrict__ ei, float* deg, int E) {
    int e = blockIdx.x * 256 + threadIdx.x;
    if (e < E) atomicAdd(&deg[ei[e]], 1.0f);  // src occurrences
}

__global__ void k_rsqrt(float* p, int n) {
    int i = blockIdx.x * 256 + threadIdx.x;
    if (i < n) p[i] = rsqrtf(p[i]);  // deg >= 1 always (self-loop)
}

__global__ void k_count(const int* __restrict__ ei, int* cnt, int E) {
    int e = blockIdx.x * 256 + threadIdx.x;
    if (e < E) atomicAdd(&cnt[ei[E + e]], 1);  // dst histogram
}

// chunk-per-thread scan of PADDED counts ((cnt+3)&~3) -> rowptr[0..n], cursor
__global__ void scan_csr(const int* __restrict__ cnt, int* __restrict__ rowptr,
                         int* __restrict__ cursor, int n) {
    __shared__ int sums[1024];
    int tid = threadIdx.x;
    int chunk = (n + 1023) >> 10;
    int lo = tid * chunk;
    int hi = min(lo + chunk, n);
    int s = 0;
    for (int i = lo; i < hi; ++i) s += (cnt[i] + 3) & ~3;
    sums[tid] = s;
    __syncthreads();
    for (int off = 1; off < 1024; off <<= 1) {
        int t = (tid >= off) ? sums[tid - off] : 0;
        __syncthreads();
        sums[tid] += t;
        __syncthreads();
    }
    int base = (tid == 0) ? 0 : sums[tid - 1];
    for (int i = lo; i < hi; ++i) {
        rowptr[i] = base;
        cursor[i] = base;
        base += (cnt[i] + 3) & ~3;
    }
    if (hi == n) rowptr[n] = base;  // every thread whose chunk ends at n writes total
}

__global__ void k_fill_csr(const int* __restrict__ ei, const float* __restrict__ dinv,
                           int* cursor, int* __restrict__ colx, float* __restrict__ wtx,
                           int E) {
    int e = blockIdx.x * 256 + threadIdx.x;
    if (e < E) {
        int s = ei[e], d = ei[E + e];
        int pos = atomicAdd(&cursor[d], 1);
        colx[pos] = s;
        wtx[pos] = dinv[s] * dinv[d];
    }
}

// ---------------- batch norm ----------------

__global__ void bn_stats(const float* __restrict__ h, float* __restrict__ stats, int n) {
    int j = threadIdx.x & 127;
    int half = threadIdx.x >> 7;  // 0/1
    float s = 0.f, q = 0.f;
    for (int r = blockIdx.x * 2 + half; r < n; r += gridDim.x * 2) {
        float v = h[r * NF + j];
        s += v;
        q += v * v;
    }
    __shared__ float ls[256], lq[256];
    ls[threadIdx.x] = s; lq[threadIdx.x] = q;
    __syncthreads();
    if (threadIdx.x < 128) {
        atomicAdd(&stats[j], ls[threadIdx.x] + ls[threadIdx.x + 128]);
        atomicAdd(&stats[NF + j], lq[threadIdx.x] + lq[threadIdx.x + 128]);
    }
}

__global__ void bn_finalize(const float* __restrict__ stats, const float* __restrict__ g,
                            const float* __restrict__ b, float* __restrict__ ac,
                            float inv_n) {
    int j = threadIdx.x;  // 128 threads
    float mean = stats[j] * inv_n;
    float var = stats[NF + j] * inv_n - mean * mean;
    float rstd = rsqrtf(var + EPS);
    float a = g[j] * rstd;
    ac[j] = a;
    ac[NF + j] = b[j] - mean * a;
}

// ---------------- GEMM: out = opt_relu( (h*a + c) @ W + opt_bias ) ----------------

__launch_bounds__(256)
__global__ void gemm_bn(const float* __restrict__ Hh, const float* __restrict__ W,
                        const float* __restrict__ ac, const float* __restrict__ bias,
                        float* __restrict__ out, int nrows, int relu) {
    __shared__ float hs[64][133];
    const int tid = threadIdx.x;
    const int tx = tid & 15;
    const int ty = tid >> 4;
    const int rb = blockIdx.x * 64;

#pragma unroll 8
    for (int p = 0; p < 32; ++p) {
        int idx = p * 256 + tid;
        int r = idx >> 7, k = idx & 127;
        int gr = rb + r;
        float v = (gr < nrows) ? Hh[(size_t)gr * NF + k] : 0.f;
        hs[r][k] = fmaf(v, ac[k], ac[NF + k]);
    }
    __syncthreads();

    float acc[4][8];
#pragma unroll
    for (int i = 0; i < 4; ++i)
#pragma unroll
        for (int j = 0; j < 8; ++j) acc[i][j] = 0.f;

    const int c0 = tx * 4, c1 = 64 + tx * 4;
#pragma unroll 4
    for (int k = 0; k < 128; ++k) {
        const float4 b0 = *(const float4*)&W[k * NF + c0];
        const float4 b1 = *(const float4*)&W[k * NF + c1];
#pragma unroll
        for (int i = 0; i < 4; ++i) {
            float a = hs[ty * 4 + i][k];
            acc[i][0] = fmaf(a, b0.x, acc[i][0]);
            acc[i][1] = fmaf(a, b0.y, acc[i][1]);
            acc[i][2] = fmaf(a, b0.z, acc[i][2]);
            acc[i][3] = fmaf(a, b0.w, acc[i][3]);
            acc[i][4] = fmaf(a, b1.x, acc[i][4]);
            acc[i][5] = fmaf(a, b1.y, acc[i][5]);
            acc[i][6] = fmaf(a, b1.z, acc[i][6]);
            acc[i][7] = fmaf(a, b1.w, acc[i][7]);
        }
    }

#pragma unroll
    for (int i = 0; i < 4; ++i) {
        int gr = rb + ty * 4 + i;
        if (gr < nrows) {
            float o[8];
#pragma unroll
            for (int j = 0; j < 8; ++j) {
                int c = (j < 4) ? (c0 + j) : (c1 + j - 4);
                float v = acc[i][j] + (bias ? bias[c] : 0.f);
                o[j] = relu ? fmaxf(v, 0.f) : v;
            }
            *(float4*)&out[(size_t)gr * NF + c0] = make_float4(o[0], o[1], o[2], o[3]);
            *(float4*)&out[(size_t)gr * NF + c1] = make_float4(o[4], o[5], o[6], o[7]);
        }
    }
}

// ---------------- GCN aggregation (padded CSR gather, 32 lanes/node, float4) ----------------
// rows padded to multiple of 4 edges; pad entries have wtx=0, colx=0.

__launch_bounds__(256)
__global__ void k_aggregate(const float* __restrict__ xw, const int* __restrict__ rowptr,
                            const int* __restrict__ colx, const float* __restrict__ wtx,
                            const float* __restrict__ dinv, const float* __restrict__ bias,
                            float* __restrict__ out, int n) {
    int node = blockIdx.x * 8 + (threadIdx.x >> 5);
    int lane = threadIdx.x & 31;
    if (node >= n) return;
    const float4* __restrict__ xw4 = (const float4*)xw;
    float di = dinv[node];
    float s2 = di * di;
    float4 self = xw4[(size_t)node * 32 + lane];
    float4 acc = make_float4(self.x * s2, self.y * s2, self.z * s2, self.w * s2);
    int e0 = rowptr[node], e1 = rowptr[node + 1];
    for (int e = e0; e < e1; e += 4) {
        int4 c4 = *(const int4*)&colx[e];
        float4 w4 = *(const float4*)&wtx[e];
        float4 v0 = xw4[(size_t)c4.x * 32 + lane];
        float4 v1 = xw4[(size_t)c4.y * 32 + lane];
        float4 v2 = xw4[(size_t)c4.z * 32 + lane];
        float4 v3 = xw4[(size_t)c4.w * 32 + lane];
        acc.x = fmaf(w4.x, v0.x, acc.x); acc.y = fmaf(w4.x, v0.y, acc.y);
        acc.z = fmaf(w4.x, v0.z, acc.z); acc.w = fmaf(w4.x, v0.w, acc.w);
        acc.x = fmaf(w4.y, v1.x, acc.x); acc.y = fmaf(w4.y, v1.y, acc.y);
        acc.z = fmaf(w4.y, v1.z, acc.z); acc.w = fmaf(w4.y, v1.w, acc.w);
        acc.x = fmaf(w4.z, v2.x, acc.x); acc.y = fmaf(w4.z, v2.y, acc.y);
        acc.z = fmaf(w4.z, v2.z, acc.z); acc.w = fmaf(w4.z, v2.w, acc.w);
        acc.x = fmaf(w4.w, v3.x, acc.x); acc.y = fmaf(w4.w, v3.y, acc.y);
        acc.z = fmaf(w4.w, v3.z, acc.z); acc.w = fmaf(w4.w, v3.w, acc.w);
    }
    float4 b4 = ((const float4*)bias)[lane];
    float4 o;
    o.x = fmaxf(acc.x + b4.x, 0.f);
    o.y = fmaxf(acc.y + b4.y, 0.f);
    o.z = fmaxf(acc.z + b4.z, 0.f);
    o.w = fmaxf(acc.w + b4.w, 0.f);
    ((float4*)out)[(size_t)node * 32 + lane] = o;
}

// ---------------- pooling (batch is sorted: segmented reduction) ----------------

__global__ void k_pool(const float* __restrict__ h, const int* __restrict__ batch,
                       float* __restrict__ pooled, int n) {
    int g = blockIdx.x;
    int t = threadIdx.x;  // 128
    int lo = 0, hi = n;
    while (lo < hi) { int m = (lo + hi) >> 1; if (batch[m] < g) lo = m + 1; else hi = m; }
    int start = lo;
    lo = start; hi = n;
    while (lo < hi) { int m = (lo + hi) >> 1; if (batch[m] < g + 1) lo = m + 1; else hi = m; }
    int end = lo;
    float a0 = 0.f, a1 = 0.f, a2 = 0.f, a3 = 0.f;
    int r = start;
    for (; r + 4 <= end; r += 4) {
        a0 += h[(size_t)r * NF + t];
        a1 += h[(size_t)(r + 1) * NF + t];
        a2 += h[(size_t)(r + 2) * NF + t];
        a3 += h[(size_t)(r + 3) * NF + t];
    }
    for (; r < end; ++r) a0 += h[(size_t)r * NF + t];
    pooled[g * NF + t] = (a0 + a1) + (a2 + a3);
}

// ---------------- classifier + log_softmax ----------------

__global__ void k_cls(const float* __restrict__ h, const float* __restrict__ ac,
                      const float* __restrict__ Wc, const float* __restrict__ bc,
                      float* __restrict__ out, int C_) {
    __shared__ float hr[128];
    __shared__ float lg[16];
    __shared__ float lse_s;
    int r = blockIdx.x, t = threadIdx.x;  // 64 threads
    hr[t]      = fmaf(h[r * NF + t],      ac[t],      ac[NF + t]);
    hr[t + 64] = fmaf(h[r * NF + 64 + t], ac[64 + t], ac[NF + 64 + t]);
    __syncthreads();
    if (t < C_) {
        float s = bc[t];
        for (int k = 0; k < 128; ++k) s = fmaf(hr[k], Wc[k * C_ + t], s);
        lg[t] = s;
    }
    __syncthreads();
    if (t == 0) {
        float m = -1e30f;
        for (int c = 0; c < C_; ++c) m = fmaxf(m, lg[c]);
        float se = 0.f;
        for (int c = 0; c < C_; ++c) se += expf(lg[c] - m);
        lse_s = m + logf(se);
    }
    __syncthreads();
    if (t < C_) out[r * C_ + t] = lg[t] - lse_s;
}

// ---------------- launch ----------------

extern "C" void kernel_launch(void* const* d_in, const int* in_sizes, int n_in,
                              void* d_out, int out_size, void* d_ws, size_t ws_size,
                              hipStream_t stream) {
    const float* x          = (const float*)d_in[0];
    const int*   ei         = (const int*)d_in[1];
    const int*   batch      = (const int*)d_in[2];
    const float* bn_feat_g  = (const float*)d_in[3];
    const float* bn_feat_b  = (const float*)d_in[4];
    const float* W_feat     = (const float*)d_in[5];
    const float* bns_conv_g = (const float*)d_in[6];
    const float* bns_conv_b = (const float*)d_in[7];
    const float* W_conv     = (const float*)d_in[8];
    const float* b_conv     = (const float*)d_in[9];
    const float* bn_fc_g    = (const float*)d_in[10];
    const float* bn_fc_b    = (const float*)d_in[11];
    const float* W_lin      = (const float*)d_in[12];
    const float* b_lin      = (const float*)d_in[13];
    const float* bn_hid_g   = (const float*)d_in[14];
    const float* bn_hid_b   = (const float*)d_in[15];
    const float* W_cls      = (const float*)d_in[16];
    const float* b_cls      = (const float*)d_in[17];
    float* outp = (float*)d_out;

    const int N_ = in_sizes[2];
    const int E_ = in_sizes[1] / 2;
    const int C_ = 10;
    const int G_ = out_size / C_;
    const int Epad = E_ + 4 * N_;  // room for per-row pad-to-4

    char* wsp = (char*)d_ws;
    auto alloc = [&](size_t bytes) {
        void* p = (void*)wsp;
        wsp += (bytes + 255) & ~(size_t)255;
        return p;
    };
    float* A      = (float*)alloc((size_t)N_ * NF * 4);
    float* B      = (float*)alloc((size_t)N_ * NF * 4);
    float* dinv   = (float*)alloc((size_t)N_ * 4);
    int*   cnt    = (int*)alloc((size_t)N_ * 4);
    int*   rowptr = (int*)alloc((size_t)(N_ + 1) * 4);
    int*   cursor = (int*)alloc((size_t)(N_ + 1) * 4);
    int*   colx   = (int*)alloc((size_t)Epad * 4);
    float* wtx    = (float*)alloc((size_t)Epad * 4);
    float* stats  = (float*)alloc(256 * 4);
    float* ac     = (float*)alloc(256 * 4);
    float* pooled = (float*)alloc((size_t)G_ * NF * 4);
    float* y2     = (float*)alloc((size_t)G_ * NF * 4);

    int nb_n = (N_ + 255) / 256;
    int nb_e = (E_ + 255) / 256;

    // graph prep
    k_fill<<<nb_n, 256, 0, stream>>>(dinv, 1.0f, N_);
    k_deg<<<nb_e, 256, 0, stream>>>(ei, dinv, E_);
    k_rsqrt<<<nb_n, 256, 0, stream>>>(dinv, N_);
    hipMemsetAsync(cnt, 0, (size_t)N_ * 4, stream);
    hipMemsetAsync(colx, 0, (size_t)Epad * 4, stream);
    hipMemsetAsync(wtx, 0, (size_t)Epad * 4, stream);
    k_count<<<nb_e, 256, 0, stream>>>(ei, cnt, E_);
    scan_csr<<<1, 1024, 0, stream>>>(cnt, rowptr, cursor, N_);
    k_fill_csr<<<nb_e, 256, 0, stream>>>(ei, dinv, cursor, colx, wtx, E_);

    // feat: h = relu( bn(x) @ W_feat )
    hipMemsetAsync(stats, 0, 256 * 4, stream);
    bn_stats<<<512, 256, 0, stream>>>(x, stats, N_);
    bn_finalize<<<1, 128, 0, stream>>>(stats, bn_feat_g, bn_feat_b, ac, 1.0f / N_);
    gemm_bn<<<(N_ + 63) / 64, 256, 0, stream>>>(x, W_feat, ac, nullptr, A, N_, 1);

    // conv layers
    for (int l = 0; l < 3; ++l) {
        hipMemsetAsync(stats, 0, 256 * 4, stream);
        bn_stats<<<512, 256, 0, stream>>>(A, stats, N_);
        bn_finalize<<<1, 128, 0, stream>>>(stats, bns_conv_g + l * NF, bns_conv_b + l * NF,
                                           ac, 1.0f / N_);
        gemm_bn<<<(N_ + 63) / 64, 256, 0, stream>>>(A, W_conv + (size_t)l * NF * NF, ac,
                                                    nullptr, B, N_, 0);
        k_aggregate<<<(N_ + 7) / 8, 256, 0, stream>>>(B, rowptr, colx, wtx, dinv,
                                                      b_conv + l * NF, A, N_);
    }

    // pool (batch sorted -> segmented reduce, no atomics)
    k_pool<<<G_, 128, 0, stream>>>(A, batch, pooled, N_);

    // fc
    hipMemsetAsync(stats, 0, 256 * 4, stream);
    bn_stats<<<512, 256, 0, stream>>>(pooled, stats, G_);
    bn_finalize<<<1, 128, 0, stream>>>(stats, bn_fc_g, bn_fc_b, ac, 1.0f / G_);
    gemm_bn<<<(G_ + 63) / 64, 256, 0, stream>>>(pooled, W_lin, ac, b_lin, y2, G_, 1);

    // classifier
    hipMemsetAsync(stats, 0, 256 * 4, stream);
    bn_stats<<<512, 256, 0, stream>>>(y2, stats, G_);
    bn_finalize<<<1, 128, 0, stream>>>(stats, bn_hid_g, bn_hid_b, ac, 1.0f / G_);
    k_cls<<<G_, 64, 0, stream>>>(y2, ac, W_cls, b_cls, outp, C_);
}

// Round 3
// 715.894 us; speedup vs baseline: 1.5872x; 1.2522x over previous
//
#include <hip/hip_runtime.h>

#define NF 128
#define EPS 1e-5f

typedef unsigned short ushort_t;
typedef unsigned int uint_t;

// ---------------- small utility kernels ----------------

__global__ void k_fill(float* p, float v, int n) {
    int i = blockIdx.x * 256 + threadIdx.x;
    if (i < n) p[i] = v;
}

__global__ void k_deg(const int* __restrict__ ei, float* deg, int E) {
    int e = blockIdx.x * 256 + threadIdx.x;
    if (e < E) atomicAdd(&deg[ei[e]], 1.0f);  // src occurrences
}

__global__ void k_rsqrt(float* p, int n) {
    int i = blockIdx.x * 256 + threadIdx.x;
    if (i < n) p[i] = rsqrtf(p[i]);  // deg >= 1 always (self-loop)
}

__global__ void k_count(const int* __restrict__ ei, int* cnt, int E) {
    int e = blockIdx.x * 256 + threadIdx.x;
    if (e < E) atomicAdd(&cnt[ei[E + e]], 1);  // dst histogram
}

// ---------------- hierarchical scan of padded counts ((cnt+3)&~3) ----------------

__global__ void scan1(const int* __restrict__ cnt, int* __restrict__ part, int n) {
    int b = blockIdx.x, t = threadIdx.x;
    int base = b * 1024 + t * 4;
    int s = 0;
#pragma unroll
    for (int k = 0; k < 4; ++k) {
        int i = base + k;
        if (i < n) s += (cnt[i] + 3) & ~3;
    }
    __shared__ int red[256];
    red[t] = s;
    __syncthreads();
    for (int off = 128; off > 0; off >>= 1) {
        if (t < off) red[t] += red[t + off];
        __syncthreads();
    }
    if (t == 0) part[b] = red[0];
}

// single small block: exclusive-scan nb partials in place, write total to rowptr[n]
__global__ void scan2(int* __restrict__ part, int* __restrict__ rowptr, int nb, int n) {
    __shared__ int lds[256];
    int t = threadIdx.x;
    int v = (t < nb) ? part[t] : 0;
    lds[t] = v;
    __syncthreads();
    for (int off = 1; off < 256; off <<= 1) {
        int x = (t >= off) ? lds[t - off] : 0;
        __syncthreads();
        lds[t] += x;
        __syncthreads();
    }
    if (t < nb) part[t] = lds[t] - v;  // exclusive
    if (t == nb - 1) rowptr[n] = lds[t];
}

__global__ void scan3(const int* __restrict__ cnt, const int* __restrict__ part,
                      int* __restrict__ rowptr, int* __restrict__ cursor, int n) {
    int b = blockIdx.x, t = threadIdx.x;
    int base = b * 1024 + t * 4;
    int c[4];
    int s = 0;
#pragma unroll
    for (int k = 0; k < 4; ++k) {
        int i = base + k;
        c[k] = (i < n) ? ((cnt[i] + 3) & ~3) : 0;
        s += c[k];
    }
    __shared__ int lds[256];
    lds[t] = s;
    __syncthreads();
    for (int off = 1; off < 256; off <<= 1) {
        int x = (t >= off) ? lds[t - off] : 0;
        __syncthreads();
        lds[t] += x;
        __syncthreads();
    }
    int run = part[b] + lds[t] - s;
#pragma unroll
    for (int k = 0; k < 4; ++k) {
        int i = base + k;
        if (i < n) {
            rowptr[i] = run;
            cursor[i] = run;
            run += c[k];
        }
    }
}

__global__ void k_fill_csr(const int* __restrict__ ei, const float* __restrict__ dinv,
                           int* cursor, int* __restrict__ colx, float* __restrict__ wtx,
                           int E) {
    int e = blockIdx.x * 256 + threadIdx.x;
    if (e < E) {
        int s = ei[e], d = ei[E + e];
        int pos = atomicAdd(&cursor[d], 1);
        colx[pos] = s;
        wtx[pos] = dinv[s] * dinv[d];
    }
}

// ---------------- batch norm ----------------

__global__ void bn_stats(const float* __restrict__ h, float* __restrict__ stats, int n) {
    int j = threadIdx.x & 127;
    int half = threadIdx.x >> 7;
    float s = 0.f, q = 0.f;
    for (int r = blockIdx.x * 2 + half; r < n; r += gridDim.x * 2) {
        float v = h[r * NF + j];
        s += v;
        q += v * v;
    }
    __shared__ float ls[256], lq[256];
    ls[threadIdx.x] = s; lq[threadIdx.x] = q;
    __syncthreads();
    if (threadIdx.x < 128) {
        atomicAdd(&stats[j], ls[threadIdx.x] + ls[threadIdx.x + 128]);
        atomicAdd(&stats[NF + j], lq[threadIdx.x] + lq[threadIdx.x + 128]);
    }
}

__global__ void bn_finalize(const float* __restrict__ stats, const float* __restrict__ g,
                            const float* __restrict__ b, float* __restrict__ ac,
                            float inv_n) {
    int j = threadIdx.x;  // 128 threads
    float mean = stats[j] * inv_n;
    float var = stats[NF + j] * inv_n - mean * mean;
    float rstd = rsqrtf(var + EPS);
    float a = g[j] * rstd;
    ac[j] = a;
    ac[NF + j] = b[j] - mean * a;
}

// ---------------- GEMM: out = opt_relu( (h*a + c) @ W + opt_bias ) ----------------
// obf!=0: write bf16 (RNE) to outb instead of fp32 to out.

static __device__ inline ushort_t f2bf(float f) {
    uint_t u = __float_as_uint(f);
    return (ushort_t)((u + 0x7fffu + ((u >> 16) & 1u)) >> 16);
}

__launch_bounds__(256)
__global__ void gemm_bn(const float* __restrict__ Hh, const float* __restrict__ W,
                        const float* __restrict__ ac, const float* __restrict__ bias,
                        float* __restrict__ out, ushort_t* __restrict__ outb,
                        int nrows, int relu, int obf) {
    __shared__ float hs[64][133];
    const int tid = threadIdx.x;
    const int tx = tid & 15;
    const int ty = tid >> 4;
    const int rb = blockIdx.x * 64;

#pragma unroll 8
    for (int p = 0; p < 32; ++p) {
        int idx = p * 256 + tid;
        int r = idx >> 7, k = idx & 127;
        int gr = rb + r;
        float v = (gr < nrows) ? Hh[(size_t)gr * NF + k] : 0.f;
        hs[r][k] = fmaf(v, ac[k], ac[NF + k]);
    }
    __syncthreads();

    float acc[4][8];
#pragma unroll
    for (int i = 0; i < 4; ++i)
#pragma unroll
        for (int j = 0; j < 8; ++j) acc[i][j] = 0.f;

    const int c0 = tx * 4, c1 = 64 + tx * 4;
#pragma unroll 4
    for (int k = 0; k < 128; ++k) {
        const float4 b0 = *(const float4*)&W[k * NF + c0];
        const float4 b1 = *(const float4*)&W[k * NF + c1];
#pragma unroll
        for (int i = 0; i < 4; ++i) {
            float a = hs[ty * 4 + i][k];
            acc[i][0] = fmaf(a, b0.x, acc[i][0]);
            acc[i][1] = fmaf(a, b0.y, acc[i][1]);
            acc[i][2] = fmaf(a, b0.z, acc[i][2]);
            acc[i][3] = fmaf(a, b0.w, acc[i][3]);
            acc[i][4] = fmaf(a, b1.x, acc[i][4]);
            acc[i][5] = fmaf(a, b1.y, acc[i][5]);
            acc[i][6] = fmaf(a, b1.z, acc[i][6]);
            acc[i][7] = fmaf(a, b1.w, acc[i][7]);
        }
    }

#pragma unroll
    for (int i = 0; i < 4; ++i) {
        int gr = rb + ty * 4 + i;
        if (gr < nrows) {
            float o[8];
#pragma unroll
            for (int j = 0; j < 8; ++j) {
                int c = (j < 4) ? (c0 + j) : (c1 + j - 4);
                float v = acc[i][j] + (bias ? bias[c] : 0.f);
                o[j] = relu ? fmaxf(v, 0.f) : v;
            }
            if (obf) {
                ushort4 p0, p1;
                p0.x = f2bf(o[0]); p0.y = f2bf(o[1]); p0.z = f2bf(o[2]); p0.w = f2bf(o[3]);
                p1.x = f2bf(o[4]); p1.y = f2bf(o[5]); p1.z = f2bf(o[6]); p1.w = f2bf(o[7]);
                *(ushort4*)&outb[(size_t)gr * NF + c0] = p0;
                *(ushort4*)&outb[(size_t)gr * NF + c1] = p1;
            } else {
                *(float4*)&out[(size_t)gr * NF + c0] = make_float4(o[0], o[1], o[2], o[3]);
                *(float4*)&out[(size_t)gr * NF + c1] = make_float4(o[4], o[5], o[6], o[7]);
            }
        }
    }
}

// ---------------- GCN aggregation (padded CSR gather, bf16 rows, 16 lanes/node) ----------------
// xwb: bf16 [n][128]. out fp32. pad entries: colx=0, wtx=0.

#define CVT2(u, a, b) { a = __uint_as_float((u) << 16); b = __uint_as_float((u) & 0xffff0000u); }

__launch_bounds__(256)
__global__ void k_aggregate_bf(const ushort_t* __restrict__ xwb, const int* __restrict__ rowptr,
                               const int* __restrict__ colx, const float* __restrict__ wtx,
                               const float* __restrict__ dinv, const float* __restrict__ bias,
                               float* __restrict__ out, int n) {
    int node = blockIdx.x * 16 + (threadIdx.x >> 4);
    int lane = threadIdx.x & 15;
    if (node >= n) return;
    const uint4* __restrict__ xq = (const uint4*)xwb;  // 16 uint4 per row (8 bf16 each)
    float di = dinv[node];
    float s2 = di * di;
    float acc[8];
    {
        uint4 q = xq[(size_t)node * 16 + lane];
        float p0, p1, p2, p3, p4, p5, p6, p7;
        CVT2(q.x, p0, p1) CVT2(q.y, p2, p3) CVT2(q.z, p4, p5) CVT2(q.w, p6, p7)
        acc[0] = p0 * s2; acc[1] = p1 * s2; acc[2] = p2 * s2; acc[3] = p3 * s2;
        acc[4] = p4 * s2; acc[5] = p5 * s2; acc[6] = p6 * s2; acc[7] = p7 * s2;
    }
    int e0 = rowptr[node], e1 = rowptr[node + 1];
    for (int e = e0; e < e1; e += 4) {
        int4 c4 = *(const int4*)&colx[e];
        float4 w4 = *(const float4*)&wtx[e];
        uint4 q0 = xq[(size_t)c4.x * 16 + lane];
        uint4 q1 = xq[(size_t)c4.y * 16 + lane];
        uint4 q2 = xq[(size_t)c4.z * 16 + lane];
        uint4 q3 = xq[(size_t)c4.w * 16 + lane];
        {
            float p0, p1, p2, p3, p4, p5, p6, p7;
            CVT2(q0.x, p0, p1) CVT2(q0.y, p2, p3) CVT2(q0.z, p4, p5) CVT2(q0.w, p6, p7)
            acc[0] = fmaf(w4.x, p0, acc[0]); acc[1] = fmaf(w4.x, p1, acc[1]);
            acc[2] = fmaf(w4.x, p2, acc[2]); acc[3] = fmaf(w4.x, p3, acc[3]);
            acc[4] = fmaf(w4.x, p4, acc[4]); acc[5] = fmaf(w4.x, p5, acc[5]);
            acc[6] = fmaf(w4.x, p6, acc[6]); acc[7] = fmaf(w4.x, p7, acc[7]);
        }
        {
            float p0, p1, p2, p3, p4, p5, p6, p7;
            CVT2(q1.x, p0, p1) CVT2(q1.y, p2, p3) CVT2(q1.z, p4, p5) CVT2(q1.w, p6, p7)
            acc[0] = fmaf(w4.y, p0, acc[0]); acc[1] = fmaf(w4.y, p1, acc[1]);
            acc[2] = fmaf(w4.y, p2, acc[2]); acc[3] = fmaf(w4.y, p3, acc[3]);
            acc[4] = fmaf(w4.y, p4, acc[4]); acc[5] = fmaf(w4.y, p5, acc[5]);
            acc[6] = fmaf(w4.y, p6, acc[6]); acc[7] = fmaf(w4.y, p7, acc[7]);
        }
        {
            float p0, p1, p2, p3, p4, p5, p6, p7;
            CVT2(q2.x, p0, p1) CVT2(q2.y, p2, p3) CVT2(q2.z, p4, p5) CVT2(q2.w, p6, p7)
            acc[0] = fmaf(w4.z, p0, acc[0]); acc[1] = fmaf(w4.z, p1, acc[1]);
            acc[2] = fmaf(w4.z, p2, acc[2]); acc[3] = fmaf(w4.z, p3, acc[3]);
            acc[4] = fmaf(w4.z, p4, acc[4]); acc[5] = fmaf(w4.z, p5, acc[5]);
            acc[6] = fmaf(w4.z, p6, acc[6]); acc[7] = fmaf(w4.z, p7, acc[7]);
        }
        {
            float p0, p1, p2, p3, p4, p5, p6, p7;
            CVT2(q3.x, p0, p1) CVT2(q3.y, p2, p3) CVT2(q3.z, p4, p5) CVT2(q3.w, p6, p7)
            acc[0] = fmaf(w4.w, p0, acc[0]); acc[1] = fmaf(w4.w, p1, acc[1]);
            acc[2] = fmaf(w4.w, p2, acc[2]); acc[3] = fmaf(w4.w, p3, acc[3]);
            acc[4] = fmaf(w4.w, p4, acc[4]); acc[5] = fmaf(w4.w, p5, acc[5]);
            acc[6] = fmaf(w4.w, p6, acc[6]); acc[7] = fmaf(w4.w, p7, acc[7]);
        }
    }
    float4 b0 = *(const float4*)&bias[lane * 8];
    float4 b1 = *(const float4*)&bias[lane * 8 + 4];
    float4 o0, o1;
    o0.x = fmaxf(acc[0] + b0.x, 0.f); o0.y = fmaxf(acc[1] + b0.y, 0.f);
    o0.z = fmaxf(acc[2] + b0.z, 0.f); o0.w = fmaxf(acc[3] + b0.w, 0.f);
    o1.x = fmaxf(acc[4] + b1.x, 0.f); o1.y = fmaxf(acc[5] + b1.y, 0.f);
    o1.z = fmaxf(acc[6] + b1.z, 0.f); o1.w = fmaxf(acc[7] + b1.w, 0.f);
    *(float4*)&out[(size_t)node * NF + lane * 8] = o0;
    *(float4*)&out[(size_t)node * NF + lane * 8 + 4] = o1;
}

// ---------------- pooling (batch is sorted: segmented reduction) ----------------

__global__ void k_pool(const float* __restrict__ h, const int* __restrict__ batch,
                       float* __restrict__ pooled, int n) {
    int g = blockIdx.x;
    int t = threadIdx.x;  // 128
    int lo = 0, hi = n;
    while (lo < hi) { int m = (lo + hi) >> 1; if (batch[m] < g) lo = m + 1; else hi = m; }
    int start = lo;
    lo = start; hi = n;
    while (lo < hi) { int m = (lo + hi) >> 1; if (batch[m] < g + 1) lo = m + 1; else hi = m; }
    int end = lo;
    float a0 = 0.f, a1 = 0.f, a2 = 0.f, a3 = 0.f;
    int r = start;
    for (; r + 4 <= end; r += 4) {
        a0 += h[(size_t)r * NF + t];
        a1 += h[(size_t)(r + 1) * NF + t];
        a2 += h[(size_t)(r + 2) * NF + t];
        a3 += h[(size_t)(r + 3) * NF + t];
    }
    for (; r < end; ++r) a0 += h[(size_t)r * NF + t];
    pooled[g * NF + t] = (a0 + a1) + (a2 + a3);
}

// ---------------- classifier + log_softmax ----------------

__global__ void k_cls(const float* __restrict__ h, const float* __restrict__ ac,
                      const float* __restrict__ Wc, const float* __restrict__ bc,
                      float* __restrict__ out, int C_) {
    __shared__ float hr[128];
    __shared__ float lg[16];
    __shared__ float lse_s;
    int r = blockIdx.x, t = threadIdx.x;  // 64 threads
    hr[t]      = fmaf(h[r * NF + t],      ac[t],      ac[NF + t]);
    hr[t + 64] = fmaf(h[r * NF + 64 + t], ac[64 + t], ac[NF + 64 + t]);
    __syncthreads();
    if (t < C_) {
        float s = bc[t];
        for (int k = 0; k < 128; ++k) s = fmaf(hr[k], Wc[k * C_ + t], s);
        lg[t] = s;
    }
    __syncthreads();
    if (t == 0) {
        float m = -1e30f;
        for (int c = 0; c < C_; ++c) m = fmaxf(m, lg[c]);
        float se = 0.f;
        for (int c = 0; c < C_; ++c) se += expf(lg[c] - m);
        lse_s = m + logf(se);
    }
    __syncthreads();
    if (t < C_) out[r * C_ + t] = lg[t] - lse_s;
}

// ---------------- launch ----------------

extern "C" void kernel_launch(void* const* d_in, const int* in_sizes, int n_in,
                              void* d_out, int out_size, void* d_ws, size_t ws_size,
                              hipStream_t stream) {
    const float* x          = (const float*)d_in[0];
    const int*   ei         = (const int*)d_in[1];
    const int*   batch      = (const int*)d_in[2];
    const float* bn_feat_g  = (const float*)d_in[3];
    const float* bn_feat_b  = (const float*)d_in[4];
    const float* W_feat     = (const float*)d_in[5];
    const float* bns_conv_g = (const float*)d_in[6];
    const float* bns_conv_b = (const float*)d_in[7];
    const float* W_conv     = (const float*)d_in[8];
    const float* b_conv     = (const float*)d_in[9];
    const float* bn_fc_g    = (const float*)d_in[10];
    const float* bn_fc_b    = (const float*)d_in[11];
    const float* W_lin      = (const float*)d_in[12];
    const float* b_lin      = (const float*)d_in[13];
    const float* bn_hid_g   = (const float*)d_in[14];
    const float* bn_hid_b   = (const float*)d_in[15];
    const float* W_cls      = (const float*)d_in[16];
    const float* b_cls      = (const float*)d_in[17];
    float* outp = (float*)d_out;

    const int N_ = in_sizes[2];
    const int E_ = in_sizes[1] / 2;
    const int C_ = 10;
    const int G_ = out_size / C_;
    const int Epad = E_ + 4 * N_;
    const int NB1 = (N_ + 1023) / 1024;  // scan blocks (<=256)

    char* wsp = (char*)d_ws;
    auto alloc = [&](size_t bytes) {
        void* p = (void*)wsp;
        wsp += (bytes + 255) & ~(size_t)255;
        return p;
    };
    float*    A      = (float*)alloc((size_t)N_ * NF * 4);
    ushort_t* Bb     = (ushort_t*)alloc((size_t)N_ * NF * 2);
    float*    dinv   = (float*)alloc((size_t)N_ * 4);
    int*      cnt    = (int*)alloc((size_t)N_ * 4);
    int*      rowptr = (int*)alloc((size_t)(N_ + 1) * 4);
    int*      cursor = (int*)alloc((size_t)(N_ + 1) * 4);
    int*      part   = (int*)alloc(256 * 4);
    int*      colx   = (int*)alloc((size_t)Epad * 4);
    float*    wtx    = (float*)alloc((size_t)Epad * 4);
    float*    stats  = (float*)alloc(256 * 4);
    float*    ac     = (float*)alloc(256 * 4);
    float*    pooled = (float*)alloc((size_t)G_ * NF * 4);
    float*    y2     = (float*)alloc((size_t)G_ * NF * 4);

    int nb_n = (N_ + 255) / 256;
    int nb_e = (E_ + 255) / 256;

    // graph prep
    k_fill<<<nb_n, 256, 0, stream>>>(dinv, 1.0f, N_);
    k_deg<<<nb_e, 256, 0, stream>>>(ei, dinv, E_);
    k_rsqrt<<<nb_n, 256, 0, stream>>>(dinv, N_);
    hipMemsetAsync(cnt, 0, (size_t)N_ * 4, stream);
    hipMemsetAsync(colx, 0, (size_t)Epad * 4, stream);
    hipMemsetAsync(wtx, 0, (size_t)Epad * 4, stream);
    k_count<<<nb_e, 256, 0, stream>>>(ei, cnt, E_);
    scan1<<<NB1, 256, 0, stream>>>(cnt, part, N_);
    scan2<<<1, 256, 0, stream>>>(part, rowptr, NB1, N_);
    scan3<<<NB1, 256, 0, stream>>>(cnt, part, rowptr, cursor, N_);
    k_fill_csr<<<nb_e, 256, 0, stream>>>(ei, dinv, cursor, colx, wtx, E_);

    // feat: h = relu( bn(x) @ W_feat )  (fp32 out -> A)
    hipMemsetAsync(stats, 0, 256 * 4, stream);
    bn_stats<<<512, 256, 0, stream>>>(x, stats, N_);
    bn_finalize<<<1, 128, 0, stream>>>(stats, bn_feat_g, bn_feat_b, ac, 1.0f / N_);
    gemm_bn<<<(N_ + 63) / 64, 256, 0, stream>>>(x, W_feat, ac, nullptr, A, nullptr, N_, 1, 0);

    // conv layers: gemm writes bf16 xw, aggregate gathers bf16, writes fp32 A
    for (int l = 0; l < 3; ++l) {
        hipMemsetAsync(stats, 0, 256 * 4, stream);
        bn_stats<<<512, 256, 0, stream>>>(A, stats, N_);
        bn_finalize<<<1, 128, 0, stream>>>(stats, bns_conv_g + l * NF, bns_conv_b + l * NF,
                                           ac, 1.0f / N_);
        gemm_bn<<<(N_ + 63) / 64, 256, 0, stream>>>(A, W_conv + (size_t)l * NF * NF, ac,
                                                    nullptr, nullptr, Bb, N_, 0, 1);
        k_aggregate_bf<<<(N_ + 15) / 16, 256, 0, stream>>>(Bb, rowptr, colx, wtx, dinv,
                                                           b_conv + l * NF, A, N_);
    }

    // pool
    k_pool<<<G_, 128, 0, stream>>>(A, batch, pooled, N_);

    // fc
    hipMemsetAsync(stats, 0, 256 * 4, stream);
    bn_stats<<<512, 256, 0, stream>>>(pooled, stats, G_);
    bn_finalize<<<1, 128, 0, stream>>>(stats, bn_fc_g, bn_fc_b, ac, 1.0f / G_);
    gemm_bn<<<(G_ + 63) / 64, 256, 0, stream>>>(pooled, W_lin, ac, b_lin, y2, nullptr, G_, 1, 0);

    // classifier
    hipMemsetAsync(stats, 0, 256 * 4, stream);
    bn_stats<<<512, 256, 0, stream>>>(y2, stats, G_);
    bn_finalize<<<1, 128, 0, stream>>>(stats, bn_hid_g, bn_hid_b, ac, 1.0f / G_);
    k_cls<<<G_, 64, 0, stream>>>(y2, ac, W_cls, b_cls, outp, C_);
}